// Round 7
// baseline (242.393 us; speedup 1.0000x reference)
//
#include <hip/hip_runtime.h>

typedef unsigned int u32;
typedef unsigned short u16;
typedef _Float16 f16;
typedef __attribute__((ext_vector_type(8))) _Float16 f16x8;
typedef __attribute__((ext_vector_type(4))) float f32x4;

#define MARGIN 1e-2f
#define LSC 2048.0f          // lo-split scale (keeps lo terms normal in f16)
#define LSCI (1.0f/2048.0f)

__device__ __forceinline__ u16 f16b(float f) {
    return __builtin_bit_cast(u16, (f16)f);
}
__device__ __forceinline__ f32x4 MF(f16x8 a, f16x8 b, f32x4 c) {
    return __builtin_amdgcn_mfma_f32_16x16x32_f16(a, b, c, 0, 0, 0);
}
__device__ __forceinline__ uint4 pack8(const u16 v[8]) {
    uint4 pk;
    pk.x = (u32)v[0] | ((u32)v[1] << 16);
    pk.y = (u32)v[2] | ((u32)v[3] << 16);
    pk.z = (u32)v[4] | ((u32)v[5] << 16);
    pk.w = (u32)v[6] | ((u32)v[7] << 16);
    return pk;
}

// ---------------------------------------------------------------------------
// conv: weights -> f16 MFMA-fragment-linear layouts (hi + scaled-lo for the
// exact-fix path). frag(nf,kk) of [K x N]: lane l (ln=l&15, quad=l>>4) holds
// 8 f16 = W[kk*32+quad*8+j][nf*16+ln], at (nf*8+kk)*512 + l*8 (u16 units).
// ---------------------------------------------------------------------------
__global__ __launch_bounds__(256) void conv_kernel(
    const float* __restrict__ Wt1, const float* __restrict__ Wp1,
    const float* __restrict__ Wt2, const float* __restrict__ Wp2,
    u16* __restrict__ wt1f, u16* __restrict__ wt1g, u16* __restrict__ wp1f,
    u16* __restrict__ wt2f, u16* __restrict__ wt2g, u16* __restrict__ wp2f,
    u32* __restrict__ gcnt)
{
    __shared__ float tile[64][68];
    const int t = threadIdx.x;
    const int b = blockIdx.x;

    if (b == 112) {
        if (t == 0) gcnt[0] = 0;
        for (int cc = t; cc < 1024; cc += 256) {
            int kk = cc >> 6, l = cc & 63, ln = l & 15, quad = l >> 4;
            u16 vh[8], vl[8];
            #pragma unroll
            for (int j = 0; j < 8; ++j) {
                int k = kk * 32 + quad * 8 + j;
                float f = (ln < 10) ? Wt2[k * 10 + ln] : 0.f;
                f16 h = (f16)f;
                vh[j] = __builtin_bit_cast(u16, h);
                vl[j] = f16b(LSC * (f - (float)h));
            }
            *(uint4*)(wt2f + kk * 512 + l * 8) = pack8(vh);
            *(uint4*)(wt2g + kk * 512 + l * 8) = pack8(vl);
        }
        for (int cc = t; cc < 2560; cc += 256) {
            int p = cc >> 8, rem = cc & 255, kk = rem >> 6, l = rem & 63;
            int ln = l & 15, quad = (l >> 4) & 3;
            u16 v[8];
            #pragma unroll
            for (int j = 0; j < 8; ++j) {
                int k = kk * 32 + quad * 8 + j;
                v[j] = f16b(ln < 10 ? Wp2[p * 1280 + k * 10 + ln] : 0.f);
            }
            *(uint4*)(wp2f + p * 2048 + kk * 512 + l * 8) = pack8(v);
        }
        return;
    }

    const float* src; int src_ld;
    u16 *dsth, *dstl; int nf0, kk0;
    if (b < 32) {
        int kt = b & 3, nt = b >> 2;
        src = Wt1 + (size_t)(kt * 64) * 512 + nt * 64; src_ld = 512;
        dsth = wt1f; dstl = wt1g; nf0 = nt * 4; kk0 = kt * 2;
    } else {
        int j = b - 32, p = j >> 3, r = j & 7;
        int kt = r & 3, nt = r >> 2;
        src = Wp1 + (size_t)p * 32768 + (size_t)(kt * 64) * 128 + nt * 64; src_ld = 128;
        dsth = wp1f + p * 32768; dstl = nullptr; nf0 = nt * 4; kk0 = kt * 2;
    }
    {
        const int kr = t >> 2, c0 = (t & 3) * 16;
        #pragma unroll
        for (int u = 0; u < 4; ++u) {
            float4 v = *(const float4*)(src + (size_t)kr * src_ld + c0 + u * 4);
            tile[kr][c0 + u*4 + 0] = v.x;
            tile[kr][c0 + u*4 + 1] = v.y;
            tile[kr][c0 + u*4 + 2] = v.z;
            tile[kr][c0 + u*4 + 3] = v.w;
        }
    }
    __syncthreads();
    #pragma unroll
    for (int s = 0; s < 2; ++s) {
        int cc = t + 256 * s;
        int l = cc & 63, fp = cc >> 6, nfl = fp >> 1, kkl = fp & 1;
        int ln = l & 15, quad = (l >> 4) & 3;
        int nloc = nfl * 16 + ln, kloc = kkl * 32 + quad * 8;
        u16 vh[8], vl[8];
        #pragma unroll
        for (int j = 0; j < 8; ++j) {
            float f = tile[kloc + j][nloc];
            f16 h = (f16)f;
            vh[j] = __builtin_bit_cast(u16, h);
            vl[j] = f16b(LSC * (f - (float)h));
        }
        size_t off = (size_t)((nf0 + nfl) * 8 + (kk0 + kkl)) * 512 + l * 8;
        *(uint4*)(dsth + off) = pack8(vh);
        if (dstl) *(uint4*)(dstl + off) = pack8(vl);
    }
}

// ---- shared macros (patch nets, used by netsum + fix) ----
#define PLD(S, KK) \
    S##0 = *(const f16x8*)(wb + (0*8+(KK))*512); \
    S##1 = *(const f16x8*)(wb + (1*8+(KK))*512); \
    S##2 = *(const f16x8*)(wb + (2*8+(KK))*512); \
    S##3 = *(const f16x8*)(wb + (3*8+(KK))*512); \
    S##4 = *(const f16x8*)(wb + (4*8+(KK))*512); \
    S##5 = *(const f16x8*)(wb + (5*8+(KK))*512); \
    S##6 = *(const f16x8*)(wb + (6*8+(KK))*512); \
    S##7 = *(const f16x8*)(wb + (7*8+(KK))*512);
#define PMF(S, KK) { f16x8 Ax_ = *(const f16x8*)(xr + (KK)*32 + quad*8); \
    a0=MF(Ax_,S##0,a0); a1=MF(Ax_,S##1,a1); a2=MF(Ax_,S##2,a2); a3=MF(Ax_,S##3,a3); \
    a4=MF(Ax_,S##4,a4); a5=MF(Ax_,S##5,a5); a6=MF(Ax_,S##6,a6); a7=MF(Ax_,S##7,a7); }
#define HPS(AC, I) { float bias_ = bp1[p*128 + (I)*16 + ln]; \
    _Pragma("unroll") for (int r_=0;r_<4;++r_){ float hv_=(AC)[r_]+bias_; hv_=hv_>0.f?hv_:0.f; \
        hp[(quad*4+r_)*140 + (I)*16+ln]=f16b(hv_);} }
#define LH(KK2) (*(const f16x8*)(&hp[ln*140 + (KK2)*32 + quad*8]))

// ---- netsum layer-1 macros ----
#define LDB(Q,KK) (*(const f16x8*)(wt1f + (size_t)((((Q)*8 + w)*8 + (KK)))*512 + lane*8))
#define LDT(Q,K2) (*(const f16x8*)(wt2f + (size_t)((Q)*4+(K2))*512 + lane*8))
#define L1MF(BB, KK) { \
    f16x8 A0_=*(const f16x8*)(&xf[0*16+ln][(KK)*32+quad*8]); \
    f16x8 A1_=*(const f16x8*)(&xf[1*16+ln][(KK)*32+quad*8]); \
    f16x8 A2_=*(const f16x8*)(&xf[2*16+ln][(KK)*32+quad*8]); \
    f16x8 A3_=*(const f16x8*)(&xf[3*16+ln][(KK)*32+quad*8]); \
    ac0=MF(A0_,BB,ac0); ac1=MF(A1_,BB,ac1); ac2=MF(A2_,BB,ac2); ac3=MF(A3_,BB,ac3); }
#define HQS(AC, M) { _Pragma("unroll") for (int r_=0;r_<4;++r_){ \
    float hv_=(AC)[r_]+bias; hv_=hv_>0.f?hv_:0.f; \
    hq[((M)*16+quad*4+r_)*140 + nloc]=f16b(hv_);} }
#define QUARTER(Q, NL) { \
    f32x4 ac0={0.f,0.f,0.f,0.f}, ac1=ac0, ac2=ac0, ac3=ac0; \
    L1MF(b0,0); if (NL) b0 = LDB((Q)+1,0); \
    L1MF(b1,1); if (NL) b1 = LDB((Q)+1,1); \
    L1MF(b2,2); if (NL) b2 = LDB((Q)+1,2); \
    L1MF(b3,3); if (NL) b3 = LDB((Q)+1,3); \
    L1MF(b4,4); if (NL) b4 = LDB((Q)+1,4); \
    L1MF(b5,5); if (NL) b5 = LDB((Q)+1,5); \
    L1MF(b6,6); if (NL) b6 = LDB((Q)+1,6); \
    L1MF(b7,7); if (NL) b7 = LDB((Q)+1,7); \
    { const int nloc = w*16+ln; const float bias = bt1[(Q)*128+nloc]; \
      HQS(ac0,0); HQS(ac1,1); HQS(ac2,2); HQS(ac3,3); } \
    __syncthreads(); \
    if (w < 4) { \
        acc2 = MF(*(const f16x8*)(&hq[(w*16+ln)*140 + 0*32 + quad*8]), t0, acc2); \
        acc2 = MF(*(const f16x8*)(&hq[(w*16+ln)*140 + 1*32 + quad*8]), t1, acc2); \
        acc2 = MF(*(const f16x8*)(&hq[(w*16+ln)*140 + 2*32 + quad*8]), t2, acc2); \
        acc2 = MF(*(const f16x8*)(&hq[(w*16+ln)*140 + 3*32 + quad*8]), t3, acc2); \
        if (NL) { t0 = LDT((Q)+1,0); t1 = LDT((Q)+1,1); t2 = LDT((Q)+1,2); t3 = LDT((Q)+1,3); } \
    } \
    __syncthreads(); }

// ---------------------------------------------------------------------------
// netsum: per 64-row block. Deep named-register prefetch: all 8 layer-1
// B-frags live in b0..b7, reloaded for quarter q+1 right after last use
// (8 loads in flight across the layer-2/barrier phase -> latency hidden).
// ---------------------------------------------------------------------------
__global__ __launch_bounds__(512, 4) void netsum_kernel(
    const float* __restrict__ x, const float* __restrict__ bt1,
    const float* __restrict__ bt2,
    const float* __restrict__ bp1, const float* __restrict__ bp2,
    const int* __restrict__ rdd,
    const u16* __restrict__ wt1f, const u16* __restrict__ wp1f,
    const u16* __restrict__ wt2f, const u16* __restrict__ wp2f,
    float* __restrict__ out, u32* __restrict__ gcnt, u32* __restrict__ glist)
{
    __shared__ u16 xf[64][264];      // 33792 B
    __shared__ u16 scratch[17920];   // 35840 B  hq[64][140] / hp 8 x [16][140]
    __shared__ float lg[64][10];
    __shared__ float oacc[64][10];
    __shared__ u32 plist[10][64];
    __shared__ u32 pcnt[10];
    __shared__ int rdds[20];
    __shared__ u32 wq[40];
    __shared__ u32 nwork;
    // ~77.6 KB -> 2 blocks/CU

    const int t = threadIdx.x;
    const int lane = t & 63;
    const int w = t >> 6;
    const int ln = lane & 15;
    const int quad = lane >> 4;
    const int row0 = blockIdx.x * 64;

    if (t < 10) pcnt[t] = 0;
    if (t < 20) rdds[t] = rdd[t];
    if (t == 0) nwork = 0;
    for (int i = t; i < 640; i += 512) ((float*)oacc)[i] = 0.f;

    // ---- stage x -> f16 LDS (coalesced) ----
    #pragma unroll
    for (int i = 0; i < 8; ++i) {
        int f = t + 512 * i;
        int r = f >> 6, c4 = f & 63;
        float4 v = *(const float4*)(x + (size_t)(row0 + r) * 256 + c4 * 4);
        u16 q0 = f16b(v.x), q1 = f16b(v.y), q2 = f16b(v.z), q3 = f16b(v.w);
        uint2 pw = { (u32)q0 | ((u32)q1 << 16), (u32)q2 | ((u32)q3 << 16) };
        *(uint2*)&xf[r][c4 * 4] = pw;
    }
    // issue quarter-0 weight prefetch before the barrier (hidden under it)
    f16x8 b0 = LDB(0,0), b1 = LDB(0,1), b2 = LDB(0,2), b3 = LDB(0,3);
    f16x8 b4 = LDB(0,4), b5 = LDB(0,5), b6 = LDB(0,6), b7 = LDB(0,7);
    f16x8 t0 = {}, t1 = {}, t2 = {}, t3 = {};
    if (w < 4) { t0 = LDT(0,0); t1 = LDT(0,1); t2 = LDT(0,2); t3 = LDT(0,3); }
    __syncthreads();

    // ---- layer 1 (4 n-quarters) + layer-2 accumulation (waves 0..3) ----
    f32x4 acc2 = (f32x4){0.f, 0.f, 0.f, 0.f};
    u16* hq = scratch;                       // [64][140]
    QUARTER(0, 1)
    QUARTER(1, 1)
    QUARTER(2, 1)
    QUARTER(3, 0)
    if (w < 4 && ln < 10) {
        #pragma unroll
        for (int r = 0; r < 4; ++r)
            lg[w * 16 + quad * 4 + r][ln] = acc2[r] + bt2[ln];
    }
    __syncthreads();

    // ---- margin flag (-> global list) + bitmap + per-patch row lists ----
    if (t < 64) {
        float l[10];
        #pragma unroll
        for (int c = 0; c < 10; ++c) l[c] = lg[t][c];
        float b0v = -1e30f; int i0 = 0;
        #pragma unroll
        for (int c = 0; c < 10; ++c) if (l[c] > b0v) { b0v = l[c]; i0 = c; }
        float b1v = -1e30f; int i1 = 0;
        #pragma unroll
        for (int c = 0; c < 10; ++c) { if (c == i0) continue; if (l[c] > b1v) { b1v = l[c]; i1 = c; } }
        float b2v = -1e30f;
        #pragma unroll
        for (int c = 0; c < 10; ++c) { if (c == i0 || c == i1) continue; if (l[c] > b2v) b2v = l[c]; }
        if (b0v - b1v < MARGIN || b1v - b2v < MARGIN) {
            u32 idx = atomicAdd(gcnt, 1u);
            glist[idx] = (u32)(row0 + t);
        }
        u32 exact = 0, fb = 0;
        #pragma unroll
        for (int p = 0; p < 10; ++p) {
            int a = rdds[2 * p], bq = rdds[2 * p + 1];
            if (i0 == a && i1 == bq) exact |= 1u << p;
            if (i0 == a)             fb    |= 1u << p;
        }
        u32 bits = exact ? exact : fb;
        while (bits) {
            int p = __ffs(bits) - 1;
            bits &= bits - 1;
            u32 idx = atomicAdd(&pcnt[p], 1u);
            plist[p][idx] = (u32)t;
        }
    }
    __syncthreads();
    if (t < 10) {
        int L = (int)pcnt[t];
        for (int base = 0; base < L; base += 16) {
            u32 e = atomicAdd(&nwork, 1u);
            wq[e] = ((u32)t << 8) | (u32)base;
        }
    }
    __syncthreads();

    // ---- gated patch nets: 8 flat n-frags, named c/d alternation ----
    {
        const u32 nw = nwork;
        for (u32 ii = w; ii < nw; ii += 8) {
            const u32 item = wq[ii];
            const int p = (int)(item >> 8), mbase = (int)(item & 255);
            const int Lp = (int)pcnt[p];
            const int mi = mbase + ln;
            const int arow = (mi < Lp) ? (int)plist[p][mi] : (int)plist[p][0];
            const u16* xr = &xf[arow][0];
            const u16* wb = wp1f + (size_t)p * 32768 + (size_t)lane * 8;
            f16x8 w20 = *(const f16x8*)(wp2f + p * 2048 + 0 * 512 + lane * 8);
            f16x8 w21 = *(const f16x8*)(wp2f + p * 2048 + 1 * 512 + lane * 8);
            f16x8 w22 = *(const f16x8*)(wp2f + p * 2048 + 2 * 512 + lane * 8);
            f16x8 w23 = *(const f16x8*)(wp2f + p * 2048 + 3 * 512 + lane * 8);
            f32x4 a0={0.f,0.f,0.f,0.f}, a1=a0, a2=a0, a3=a0, a4=a0, a5=a0, a6=a0, a7=a0;
            f16x8 c0,c1,c2,c3,c4,c5,c6,c7, d0,d1,d2,d3,d4,d5,d6,d7;
            PLD(c,0);
            PLD(d,1); PMF(c,0);
            PLD(c,2); PMF(d,1);
            PLD(d,3); PMF(c,2);
            PLD(c,4); PMF(d,3);
            PLD(d,5); PMF(c,4);
            PLD(c,6); PMF(d,5);
            PLD(d,7); PMF(c,6);
            PMF(d,7);
            u16* hp = scratch + w * 2240;            // [16][140]
            HPS(a0,0); HPS(a1,1); HPS(a2,2); HPS(a3,3);
            HPS(a4,4); HPS(a5,5); HPS(a6,6); HPS(a7,7);
            f32x4 po = (f32x4){0.f,0.f,0.f,0.f};
            po = MF(LH(0), w20, po);
            po = MF(LH(1), w21, po);
            po = MF(LH(2), w22, po);
            po = MF(LH(3), w23, po);
            if (ln < 10) {
                float b2 = bp2[p * 10 + ln];
                #pragma unroll
                for (int r = 0; r < 4; ++r) {
                    int mi2 = mbase + quad * 4 + r;
                    if (mi2 < Lp)
                        atomicAdd(&oacc[plist[p][mi2]][ln], po[r] + b2);
                }
            }
        }
    }
    __syncthreads();

    for (int i = t; i < 640; i += 512)
        out[(size_t)row0 * 10 + i] = ((float*)lg)[i] + ((float*)oacc)[i];
}

// ---- fix layer-1 macros ----
#define FLD(S,KK) \
    S##h0 = *(const f16x8*)(bbh + (KK)*512); \
    S##h1 = *(const f16x8*)(bbh + 4096 + (KK)*512); \
    S##l0 = *(const f16x8*)(bbl + (KK)*512); \
    S##l1 = *(const f16x8*)(bbl + 4096 + (KK)*512);
#define FCP(S,KK) { _Pragma("unroll") for (int m_=0;m_<4;++m_){ \
    f16x8 ah_=*(const f16x8*)(&xfh[m_*16+ln][(KK)*32+quad*8]); \
    f16x8 al_=*(const f16x8*)(&xfl[m_*16+ln][(KK)*32+quad*8]); \
    accH[m_][0]=MF(ah_,S##h0,accH[m_][0]); accS[m_][0]=MF(ah_,S##l0,accS[m_][0]); accS[m_][0]=MF(al_,S##h0,accS[m_][0]); \
    accH[m_][1]=MF(ah_,S##h1,accH[m_][1]); accS[m_][1]=MF(ah_,S##l1,accS[m_][1]); accS[m_][1]=MF(al_,S##h1,accS[m_][1]); } }
#define F2L(WH, WL, KK) \
    WH = *(const f16x8*)(wt2f + (hl*8+(KK))*512 + lane*8); \
    WL = *(const f16x8*)(wt2g + (hl*8+(KK))*512 + lane*8);
#define F2C(WH, WL, KK) { int hidx_=(w*16+ln)*264 + (KK)*32 + quad*8; \
    f16x8 hah_=*(const f16x8*)(&hb2[0][hidx_]); f16x8 hal_=*(const f16x8*)(&hb2[1][hidx_]); \
    acc2h=MF(hah_,WH,acc2h); acc2s=MF(hah_,WL,acc2s); acc2s=MF(hal_,WH,acc2s); }

// ---------------------------------------------------------------------------
// fix: high-precision recompute for margin-flagged rows, MFMA throughout.
// Split-f16 (hi + 2048*lo) layer1+2 reproduces fp32 logits to ~1e-7 ->
// exact bitmap; patch nets plain f16 MFMA. Alternating named-reg prefetch.
// ---------------------------------------------------------------------------
__global__ __launch_bounds__(512, 1) void fix_kernel(
    const float* __restrict__ x, const float* __restrict__ bt1,
    const float* __restrict__ bt2,
    const float* __restrict__ bp1, const float* __restrict__ bp2,
    const int* __restrict__ rdd,
    const u16* __restrict__ wt1f, const u16* __restrict__ wt1g,
    const u16* __restrict__ wt2f, const u16* __restrict__ wt2g,
    const u16* __restrict__ wp1f, const u16* __restrict__ wp2f,
    const u32* __restrict__ gcnt, const u32* __restrict__ glist,
    float* __restrict__ out)
{
    __shared__ u16 xfh[64][264];
    __shared__ u16 xfl[64][264];
    __shared__ u16 hb2[2][16896];    // h hi/lo halves; reused as patch hp
    __shared__ float lg[64][10];
    __shared__ float oacc[64][10];
    __shared__ u32 rows[64];
    __shared__ u32 plist[10][64];
    __shared__ u32 pcnt[10];
    __shared__ int rdds[20];
    __shared__ u32 wq[40];
    __shared__ u32 nwork;
    // ~143 KB -> 1 block/CU

    const int t = threadIdx.x;
    const int lane = t & 63;
    const int w = t >> 6;
    const int ln = lane & 15;
    const int quad = lane >> 4;
    const u32 cnt = gcnt[0];
    if (t < 20) rdds[t] = rdd[t];

    for (u32 base = blockIdx.x * 64; base < cnt; base += gridDim.x * 64) {
        __syncthreads();
        const int R = (int)min(64u, cnt - base);
        if (t < 64) rows[t] = glist[base + (t < R ? t : 0)];
        if (t < 10) pcnt[t] = 0;
        if (t == 0) nwork = 0;
        for (int i = t; i < 640; i += 512) ((float*)oacc)[i] = 0.f;
        __syncthreads();

        // ---- gather flagged x rows -> hi/lo f16 LDS ----
        #pragma unroll
        for (int i = 0; i < 8; ++i) {
            int f = t + 512 * i;
            int r = f >> 6, c4 = f & 63;
            float4 v = *(const float4*)(x + (size_t)rows[r] * 256 + c4 * 4);
            f16 h0 = (f16)v.x, h1 = (f16)v.y, h2 = (f16)v.z, h3 = (f16)v.w;
            u16 q0 = __builtin_bit_cast(u16, h0), q1 = __builtin_bit_cast(u16, h1);
            u16 q2 = __builtin_bit_cast(u16, h2), q3 = __builtin_bit_cast(u16, h3);
            u16 l0 = f16b(LSC * (v.x - (float)h0)), l1 = f16b(LSC * (v.y - (float)h1));
            u16 l2 = f16b(LSC * (v.z - (float)h2)), l3 = f16b(LSC * (v.w - (float)h3));
            uint2 hw = { (u32)q0 | ((u32)q1 << 16), (u32)q2 | ((u32)q3 << 16) };
            uint2 lw = { (u32)l0 | ((u32)l1 << 16), (u32)l2 | ((u32)l3 << 16) };
            *(uint2*)&xfh[r][c4 * 4] = hw;
            *(uint2*)&xfl[r][c4 * 4] = lw;
        }
        __syncthreads();

        // ---- layer 1 split-f16 (3 MFMA) + layer 2 split-f16 (3 MFMA) ----
        f32x4 acc2h = (f32x4){0.f,0.f,0.f,0.f};
        f32x4 acc2s = (f32x4){0.f,0.f,0.f,0.f};
        for (int hl = 0; hl < 2; ++hl) {
            f32x4 accH[4][2], accS[4][2];
            #pragma unroll
            for (int m = 0; m < 4; ++m)
                #pragma unroll
                for (int i2 = 0; i2 < 2; ++i2) {
                    accH[m][i2] = (f32x4){0.f,0.f,0.f,0.f};
                    accS[m][i2] = (f32x4){0.f,0.f,0.f,0.f};
                }
            const size_t boff = (size_t)(hl * 16 + w * 2) * 4096 + (size_t)lane * 8;
            const u16* bbh = wt1f + boff;
            const u16* bbl = wt1g + boff;
            f16x8 ch0, ch1, cl0, cl1, nh0, nh1, nl0, nl1;
            FLD(c,0);
            FLD(n,1); FCP(c,0);
            FLD(c,2); FCP(n,1);
            FLD(n,3); FCP(c,2);
            FLD(c,4); FCP(n,3);
            FLD(n,5); FCP(c,4);
            FLD(c,6); FCP(n,5);
            FLD(n,7); FCP(c,6);
            FCP(n,7);
            // bias + relu + hi/lo split -> hb2
            #pragma unroll
            for (int m = 0; m < 4; ++m)
                #pragma unroll
                for (int i2 = 0; i2 < 2; ++i2) {
                    int nloc = w * 32 + i2 * 16 + ln;
                    float bias = bt1[hl * 256 + nloc];
                    #pragma unroll
                    for (int r = 0; r < 4; ++r) {
                        float hv = accH[m][i2][r] + accS[m][i2][r] * LSCI + bias;
                        hv = hv > 0.f ? hv : 0.f;
                        f16 hh = (f16)hv;
                        int idx = (m * 16 + quad * 4 + r) * 264 + nloc;
                        hb2[0][idx] = __builtin_bit_cast(u16, hh);
                        hb2[1][idx] = f16b(LSC * (hv - (float)hh));
                    }
                }
            __syncthreads();
            if (w < 4) {
                f16x8 whc, wlc, whn, wln;
                F2L(whc, wlc, 0);
                F2L(whn, wln, 1); F2C(whc, wlc, 0);
                F2L(whc, wlc, 2); F2C(whn, wln, 1);
                F2L(whn, wln, 3); F2C(whc, wlc, 2);
                F2L(whc, wlc, 4); F2C(whn, wln, 3);
                F2L(whn, wln, 5); F2C(whc, wlc, 4);
                F2L(whc, wlc, 6); F2C(whn, wln, 5);
                F2L(whn, wln, 7); F2C(whc, wlc, 6);
                F2C(whn, wln, 7);
            }
            __syncthreads();
        }
        if (w < 4 && ln < 10) {
            #pragma unroll
            for (int r = 0; r < 4; ++r)
                lg[w * 16 + quad * 4 + r][ln] = acc2h[r] + acc2s[r] * LSCI + bt2[ln];
        }
        __syncthreads();

        // ---- exact bitmap + per-patch row lists ----
        if (t < R) {
            float l[10];
            #pragma unroll
            for (int c = 0; c < 10; ++c) l[c] = lg[t][c];
            float b0v = -1e30f; int i0 = 0;
            #pragma unroll
            for (int c = 0; c < 10; ++c) if (l[c] > b0v) { b0v = l[c]; i0 = c; }
            float b1v = -1e30f; int i1 = 0;
            #pragma unroll
            for (int c = 0; c < 10; ++c) { if (c == i0) continue; if (l[c] > b1v) { b1v = l[c]; i1 = c; } }
            u32 exact = 0, fb = 0;
            #pragma unroll
            for (int p = 0; p < 10; ++p) {
                int a = rdds[2 * p], bq = rdds[2 * p + 1];
                if (i0 == a && i1 == bq) exact |= 1u << p;
                if (i0 == a)             fb    |= 1u << p;
            }
            u32 bits = exact ? exact : fb;
            while (bits) {
                int p = __ffs(bits) - 1;
                bits &= bits - 1;
                u32 idx = atomicAdd(&pcnt[p], 1u);
                plist[p][idx] = (u32)t;
            }
        }
        __syncthreads();
        if (t < 10) {
            int L = (int)pcnt[t];
            for (int b2i = 0; b2i < L; b2i += 16) {
                u32 e = atomicAdd(&nwork, 1u);
                wq[e] = ((u32)t << 8) | (u32)b2i;
            }
        }
        __syncthreads();

        // ---- patch nets: flattened 8-frag named alternation ----
        {
            const u32 nw = nwork;
            u16* hbase = &hb2[0][0];
            for (u32 ii = w; ii < nw; ii += 8) {
                const u32 item = wq[ii];
                const int p = (int)(item >> 8), mbase = (int)(item & 255);
                const int Lp = (int)pcnt[p];
                const int mi = mbase + ln;
                const int arow = (mi < Lp) ? (int)plist[p][mi] : (int)plist[p][0];
                const u16* xr = &xfh[arow][0];
                const u16* wb = wp1f + (size_t)p * 32768 + (size_t)lane * 8;
                f16x8 w20 = *(const f16x8*)(wp2f + p * 2048 + 0 * 512 + lane * 8);
                f16x8 w21 = *(const f16x8*)(wp2f + p * 2048 + 1 * 512 + lane * 8);
                f16x8 w22 = *(const f16x8*)(wp2f + p * 2048 + 2 * 512 + lane * 8);
                f16x8 w23 = *(const f16x8*)(wp2f + p * 2048 + 3 * 512 + lane * 8);
                f32x4 a0={0.f,0.f,0.f,0.f}, a1=a0, a2=a0, a3=a0, a4=a0, a5=a0, a6=a0, a7=a0;
                f16x8 c0,c1,c2,c3,c4,c5,c6,c7, d0,d1,d2,d3,d4,d5,d6,d7;
                PLD(c,0);
                PLD(d,1); PMF(c,0);
                PLD(c,2); PMF(d,1);
                PLD(d,3); PMF(c,2);
                PLD(c,4); PMF(d,3);
                PLD(d,5); PMF(c,4);
                PLD(c,6); PMF(d,5);
                PLD(d,7); PMF(c,6);
                PMF(d,7);
                u16* hp = hbase + w * 2240;          // [16][140]
                HPS(a0,0); HPS(a1,1); HPS(a2,2); HPS(a3,3);
                HPS(a4,4); HPS(a5,5); HPS(a6,6); HPS(a7,7);
                f32x4 po = (f32x4){0.f,0.f,0.f,0.f};
                po = MF(LH(0), w20, po);
                po = MF(LH(1), w21, po);
                po = MF(LH(2), w22, po);
                po = MF(LH(3), w23, po);
                if (ln < 10) {
                    float b2 = bp2[p * 10 + ln];
                    #pragma unroll
                    for (int r = 0; r < 4; ++r) {
                        int mi2 = mbase + quad * 4 + r;
                        if (mi2 < Lp)
                            atomicAdd(&oacc[plist[p][mi2]][ln], po[r] + b2);
                    }
                }
            }
        }
        __syncthreads();

        for (int i = t; i < R * 10; i += 512) {
            int r = i / 10, c = i % 10;
            out[(size_t)rows[r] * 10 + c] = lg[r][c] + oacc[r][c];
        }
    }
}

extern "C" void kernel_launch(void* const* d_in, const int* in_sizes, int n_in,
                              void* d_out, int out_size, void* d_ws, size_t ws_size,
                              hipStream_t stream) {
    const float* x   = (const float*)d_in[0];
    const float* Wt1 = (const float*)d_in[1];
    const float* bt1 = (const float*)d_in[2];
    const float* Wt2 = (const float*)d_in[3];
    const float* bt2 = (const float*)d_in[4];
    const float* Wp1 = (const float*)d_in[5];
    const float* bp1 = (const float*)d_in[6];
    const float* Wp2 = (const float*)d_in[7];
    const float* bp2 = (const float*)d_in[8];
    const int* rdd = (const int*)d_in[9];
    float* out = (float*)d_out;

    u16* wt1f = (u16*)d_ws;                 // 131072 u16
    u16* wt1g = wt1f + 131072;              // 131072 u16
    u16* wp1f = wt1g + 131072;              // 327680 u16
    u16* wt2f = wp1f + 327680;              // 8192 u16
    u16* wt2g = wt2f + 8192;                // 8192 u16
    u16* wp2f = wt2g + 8192;                // 20480 u16
    u32* gcnt  = (u32*)(wp2f + 20480);      // 1 (+pad to 16)
    u32* glist = gcnt + 16;                 // 65536 u32

    hipLaunchKernelGGL(conv_kernel, dim3(113), dim3(256), 0, stream,
                       Wt1, Wp1, Wt2, Wp2, wt1f, wt1g, wp1f, wt2f, wt2g, wp2f, gcnt);
    hipLaunchKernelGGL(netsum_kernel, dim3(1024), dim3(512), 0, stream,
                       x, bt1, bt2, bp1, bp2, rdd,
                       wt1f, wp1f, wt2f, wp2f, out, gcnt, glist);
    hipLaunchKernelGGL(fix_kernel, dim3(256), dim3(512), 0, stream,
                       x, bt1, bt2, bp1, bp2, rdd,
                       wt1f, wt1g, wt2f, wt2g, wp1f, wp2f,
                       gcnt, glist, out);
}

// Round 8
// 220.965 us; speedup vs baseline: 1.0970x; 1.0970x over previous
//
#include <hip/hip_runtime.h>

typedef unsigned int u32;
typedef unsigned short u16;
typedef _Float16 f16;
typedef __attribute__((ext_vector_type(8))) _Float16 f16x8;
typedef __attribute__((ext_vector_type(4))) float f32x4;

#define MARGIN 1e-2f
#define LSC 2048.0f          // lo-split scale (keeps lo terms normal in f16)
#define LSCI (1.0f/2048.0f)

__device__ __forceinline__ u16 f16b(float f) {
    return __builtin_bit_cast(u16, (f16)f);
}
__device__ __forceinline__ f32x4 MF(f16x8 a, f16x8 b, f32x4 c) {
    return __builtin_amdgcn_mfma_f32_16x16x32_f16(a, b, c, 0, 0, 0);
}
__device__ __forceinline__ uint4 pack8(const u16 v[8]) {
    uint4 pk;
    pk.x = (u32)v[0] | ((u32)v[1] << 16);
    pk.y = (u32)v[2] | ((u32)v[3] << 16);
    pk.z = (u32)v[4] | ((u32)v[5] << 16);
    pk.w = (u32)v[6] | ((u32)v[7] << 16);
    return pk;
}

// ---------------------------------------------------------------------------
// conv: weights -> f16 MFMA-fragment-linear layouts (hi + scaled-lo for the
// exact-fix path). frag(nf,kk) of [K x N]: lane l (ln=l&15, quad=l>>4) holds
// 8 f16 = W[kk*32+quad*8+j][nf*16+ln], at (nf*8+kk)*512 + l*8 (u16 units).
// ---------------------------------------------------------------------------
__global__ __launch_bounds__(256) void conv_kernel(
    const float* __restrict__ Wt1, const float* __restrict__ Wp1,
    const float* __restrict__ Wt2, const float* __restrict__ Wp2,
    u16* __restrict__ wt1f, u16* __restrict__ wt1g, u16* __restrict__ wp1f,
    u16* __restrict__ wt2f, u16* __restrict__ wt2g, u16* __restrict__ wp2f,
    u32* __restrict__ gcnt)
{
    __shared__ float tile[64][68];
    const int t = threadIdx.x;
    const int b = blockIdx.x;

    if (b == 112) {
        if (t == 0) gcnt[0] = 0;
        for (int cc = t; cc < 1024; cc += 256) {
            int kk = cc >> 6, l = cc & 63, ln = l & 15, quad = l >> 4;
            u16 vh[8], vl[8];
            #pragma unroll
            for (int j = 0; j < 8; ++j) {
                int k = kk * 32 + quad * 8 + j;
                float f = (ln < 10) ? Wt2[k * 10 + ln] : 0.f;
                f16 h = (f16)f;
                vh[j] = __builtin_bit_cast(u16, h);
                vl[j] = f16b(LSC * (f - (float)h));
            }
            *(uint4*)(wt2f + kk * 512 + l * 8) = pack8(vh);
            *(uint4*)(wt2g + kk * 512 + l * 8) = pack8(vl);
        }
        for (int cc = t; cc < 2560; cc += 256) {
            int p = cc >> 8, rem = cc & 255, kk = rem >> 6, l = rem & 63;
            int ln = l & 15, quad = (l >> 4) & 3;
            u16 v[8];
            #pragma unroll
            for (int j = 0; j < 8; ++j) {
                int k = kk * 32 + quad * 8 + j;
                v[j] = f16b(ln < 10 ? Wp2[p * 1280 + k * 10 + ln] : 0.f);
            }
            *(uint4*)(wp2f + p * 2048 + kk * 512 + l * 8) = pack8(v);
        }
        return;
    }

    const float* src; int src_ld;
    u16 *dsth, *dstl; int nf0, kk0;
    if (b < 32) {
        int kt = b & 3, nt = b >> 2;
        src = Wt1 + (size_t)(kt * 64) * 512 + nt * 64; src_ld = 512;
        dsth = wt1f; dstl = wt1g; nf0 = nt * 4; kk0 = kt * 2;
    } else {
        int j = b - 32, p = j >> 3, r = j & 7;
        int kt = r & 3, nt = r >> 2;
        src = Wp1 + (size_t)p * 32768 + (size_t)(kt * 64) * 128 + nt * 64; src_ld = 128;
        dsth = wp1f + p * 32768; dstl = nullptr; nf0 = nt * 4; kk0 = kt * 2;
    }
    {
        const int kr = t >> 2, c0 = (t & 3) * 16;
        #pragma unroll
        for (int u = 0; u < 4; ++u) {
            float4 v = *(const float4*)(src + (size_t)kr * src_ld + c0 + u * 4);
            tile[kr][c0 + u*4 + 0] = v.x;
            tile[kr][c0 + u*4 + 1] = v.y;
            tile[kr][c0 + u*4 + 2] = v.z;
            tile[kr][c0 + u*4 + 3] = v.w;
        }
    }
    __syncthreads();
    #pragma unroll
    for (int s = 0; s < 2; ++s) {
        int cc = t + 256 * s;
        int l = cc & 63, fp = cc >> 6, nfl = fp >> 1, kkl = fp & 1;
        int ln = l & 15, quad = (l >> 4) & 3;
        int nloc = nfl * 16 + ln, kloc = kkl * 32 + quad * 8;
        u16 vh[8], vl[8];
        #pragma unroll
        for (int j = 0; j < 8; ++j) {
            float f = tile[kloc + j][nloc];
            f16 h = (f16)f;
            vh[j] = __builtin_bit_cast(u16, h);
            vl[j] = f16b(LSC * (f - (float)h));
        }
        size_t off = (size_t)((nf0 + nfl) * 8 + (kk0 + kkl)) * 512 + l * 8;
        *(uint4*)(dsth + off) = pack8(vh);
        if (dstl) *(uint4*)(dstl + off) = pack8(vl);
    }
}

// ---- shared patch-net macros (netsum + fix) ----
#define PLD(S, KK) \
    S##0 = *(const f16x8*)(wb + (0*8+(KK))*512); \
    S##1 = *(const f16x8*)(wb + (1*8+(KK))*512); \
    S##2 = *(const f16x8*)(wb + (2*8+(KK))*512); \
    S##3 = *(const f16x8*)(wb + (3*8+(KK))*512); \
    S##4 = *(const f16x8*)(wb + (4*8+(KK))*512); \
    S##5 = *(const f16x8*)(wb + (5*8+(KK))*512); \
    S##6 = *(const f16x8*)(wb + (6*8+(KK))*512); \
    S##7 = *(const f16x8*)(wb + (7*8+(KK))*512);
#define PMF(S, KK) { f16x8 Ax_ = *(const f16x8*)(xr + (KK)*32 + quad*8); \
    a0=MF(Ax_,S##0,a0); a1=MF(Ax_,S##1,a1); a2=MF(Ax_,S##2,a2); a3=MF(Ax_,S##3,a3); \
    a4=MF(Ax_,S##4,a4); a5=MF(Ax_,S##5,a5); a6=MF(Ax_,S##6,a6); a7=MF(Ax_,S##7,a7); }
#define HPS(AC, I) { float bias_ = bp1[p*128 + (I)*16 + ln]; \
    _Pragma("unroll") for (int r_=0;r_<4;++r_){ float hv_=(AC)[r_]+bias_; hv_=hv_>0.f?hv_:0.f; \
        hp[(quad*4+r_)*140 + (I)*16+ln]=f16b(hv_);} }
#define LH(KK2) (*(const f16x8*)(&hp[ln*140 + (KK2)*32 + quad*8]))

// ---- netsum layer-1 depth-4 pipeline step ----
#define K1(BREG, KK, NSRC, NKK) { \
    f16x8 a0_ = *(const f16x8*)(&xf[ln][(KK)*32 + quad*8]); \
    f16x8 a1_ = *(const f16x8*)(&xf[16 + ln][(KK)*32 + quad*8]); \
    ac0 = MF(a0_, BREG, ac0); ac1 = MF(a1_, BREG, ac1); \
    BREG = *(const f16x8*)((NSRC) + (NKK)*512); }

// ---------------------------------------------------------------------------
// netsum v8: 32-row / 4-wave blocks (grid 2048), launch_bounds(256,2) ->
// 256-VGPR budget (R7's 64-VGPR pin caused 158 MB of spill traffic).
// Layer-1 is barrier-free: wave w owns n-quarter w, depth-4 rotating
// named-register B prefetch, h streamed to LDS. One barrier, then layer-2
// on all 4 waves (k-frags w,w+4,w+8,w+12 -> lg atomicAdd partials).
// ---------------------------------------------------------------------------
__global__ __launch_bounds__(256, 2) void netsum_kernel(
    const float* __restrict__ x, const float* __restrict__ bt1,
    const float* __restrict__ bt2,
    const float* __restrict__ bp1, const float* __restrict__ bp2,
    const int* __restrict__ rdd,
    const u16* __restrict__ wt1f, const u16* __restrict__ wp1f,
    const u16* __restrict__ wt2f, const u16* __restrict__ wp2f,
    float* __restrict__ out, u32* __restrict__ gcnt, u32* __restrict__ glist)
{
    __shared__ u16 xf[32][264];      // 16896 B  x in f16
    __shared__ u16 hl[17152];        // 34304 B  h [32][536]; patch hp overlay 4x2240
    __shared__ float lg[32][10];
    __shared__ float oacc[32][10];
    __shared__ u32 plist[10][32];
    __shared__ u32 pcnt[10];
    __shared__ int rdds[20];
    __shared__ u32 wq[24];
    __shared__ u32 nwork;
    // ~54 KB -> 2 blocks/CU (8 waves), barrier groups decoupled across blocks

    const int t = threadIdx.x;
    const int lane = t & 63;
    const int w = t >> 6;
    const int ln = lane & 15;
    const int quad = lane >> 4;
    const int row0 = blockIdx.x * 32;

    if (t < 10) pcnt[t] = 0;
    if (t < 20) rdds[t] = rdd[t];
    if (t == 0) nwork = 0;
    for (int i = t; i < 320; i += 256) {
        ((float*)lg)[i] = bt2[i % 10];
        ((float*)oacc)[i] = 0.f;
    }

    // ---- stage x -> f16 LDS (coalesced) ----
    #pragma unroll
    for (int i = 0; i < 8; ++i) {
        int f = t + 256 * i;           // float4 index 0..2047
        int r = f >> 6, c4 = f & 63;
        float4 v = *(const float4*)(x + (size_t)(row0 + r) * 256 + c4 * 4);
        u16 q0 = f16b(v.x), q1 = f16b(v.y), q2 = f16b(v.z), q3 = f16b(v.w);
        uint2 pw = { (u32)q0 | ((u32)q1 << 16), (u32)q2 | ((u32)q3 << 16) };
        *(uint2*)&xf[r][c4 * 4] = pw;
    }
    // issue first 4 B-frag loads before the barrier (hidden under it)
    const u16* bbase = wt1f + (size_t)(w * 64) * 512 + (size_t)lane * 8;
    f16x8 bA = *(const f16x8*)(bbase + 0 * 512);
    f16x8 bB = *(const f16x8*)(bbase + 1 * 512);
    f16x8 bC = *(const f16x8*)(bbase + 2 * 512);
    f16x8 bD = *(const f16x8*)(bbase + 3 * 512);
    __syncthreads();

    // ---- layer 1: wave-private n-quarter, no barriers, depth-4 pipeline ----
    for (int f = 0; f < 8; ++f) {
        const int fn = (f < 7) ? f + 1 : 7;
        const u16* bc = bbase + (size_t)(f * 8) * 512;
        const u16* bn = bbase + (size_t)(fn * 8) * 512;
        f32x4 ac0 = (f32x4){0.f,0.f,0.f,0.f}, ac1 = ac0;
        K1(bA, 0, bc, 4)
        K1(bB, 1, bc, 5)
        K1(bC, 2, bc, 6)
        K1(bD, 3, bc, 7)
        K1(bA, 4, bn, 0)
        K1(bB, 5, bn, 1)
        K1(bC, 6, bn, 2)
        K1(bD, 7, bn, 3)
        // bias + relu + f16 -> hl [32][536]
        const int ncol = w * 128 + f * 16 + ln;
        const float bias = bt1[ncol];
        #pragma unroll
        for (int r = 0; r < 4; ++r) {
            float h0 = ac0[r] + bias; h0 = h0 > 0.f ? h0 : 0.f;
            float h1 = ac1[r] + bias; h1 = h1 > 0.f ? h1 : 0.f;
            hl[(quad * 4 + r) * 536 + ncol] = f16b(h0);
            hl[(16 + quad * 4 + r) * 536 + ncol] = f16b(h1);
        }
    }
    __syncthreads();

    // ---- layer 2: all 4 waves; wave w takes k-frags w, w+4, w+8, w+12 ----
    {
        f16x8 w0 = *(const f16x8*)(wt2f + (w + 0) * 512 + lane * 8);
        f16x8 w1 = *(const f16x8*)(wt2f + (w + 4) * 512 + lane * 8);
        f16x8 w2 = *(const f16x8*)(wt2f + (w + 8) * 512 + lane * 8);
        f16x8 w3 = *(const f16x8*)(wt2f + (w + 12) * 512 + lane * 8);
        f32x4 p0 = (f32x4){0.f,0.f,0.f,0.f}, p1 = p0;
        #pragma unroll
        for (int j = 0; j < 4; ++j) {
            const int kf = w + j * 4;
            f16x8 wb = (j == 0) ? w0 : (j == 1) ? w1 : (j == 2) ? w2 : w3;
            f16x8 a0 = *(const f16x8*)(&hl[(ln) * 536 + kf * 32 + quad * 8]);
            f16x8 a1 = *(const f16x8*)(&hl[(16 + ln) * 536 + kf * 32 + quad * 8]);
            p0 = MF(a0, wb, p0);
            p1 = MF(a1, wb, p1);
        }
        if (ln < 10) {
            #pragma unroll
            for (int r = 0; r < 4; ++r) {
                atomicAdd(&lg[quad * 4 + r][ln], p0[r]);
                atomicAdd(&lg[16 + quad * 4 + r][ln], p1[r]);
            }
        }
    }
    __syncthreads();

    // ---- margin flag (-> global list) + bitmap + per-patch row lists ----
    if (t < 32) {
        float l[10];
        #pragma unroll
        for (int c = 0; c < 10; ++c) l[c] = lg[t][c];
        float b0v = -1e30f; int i0 = 0;
        #pragma unroll
        for (int c = 0; c < 10; ++c) if (l[c] > b0v) { b0v = l[c]; i0 = c; }
        float b1v = -1e30f; int i1 = 0;
        #pragma unroll
        for (int c = 0; c < 10; ++c) { if (c == i0) continue; if (l[c] > b1v) { b1v = l[c]; i1 = c; } }
        float b2v = -1e30f;
        #pragma unroll
        for (int c = 0; c < 10; ++c) { if (c == i0 || c == i1) continue; if (l[c] > b2v) b2v = l[c]; }
        if (b0v - b1v < MARGIN || b1v - b2v < MARGIN) {
            u32 idx = atomicAdd(gcnt, 1u);
            glist[idx] = (u32)(row0 + t);
        }
        u32 exact = 0, fb = 0;
        #pragma unroll
        for (int p = 0; p < 10; ++p) {
            int a = rdds[2 * p], bq = rdds[2 * p + 1];
            if (i0 == a && i1 == bq) exact |= 1u << p;
            if (i0 == a)             fb    |= 1u << p;
        }
        u32 bits = exact ? exact : fb;
        while (bits) {
            int p = __ffs(bits) - 1;
            bits &= bits - 1;
            u32 idx = atomicAdd(&pcnt[p], 1u);
            plist[p][idx] = (u32)t;
        }
    }
    __syncthreads();
    if (t < 10) {
        int L = (int)pcnt[t];
        for (int base = 0; base < L; base += 16) {
            u32 e = atomicAdd(&nwork, 1u);
            wq[e] = ((u32)t << 8) | (u32)base;
        }
    }
    __syncthreads();

    // ---- gated patch nets: 8 flat n-frags, depth-8 named arrays (256-VGPR ok) ----
    {
        const u32 nw = nwork;
        for (u32 ii = w; ii < nw; ii += 4) {
            const u32 item = wq[ii];
            const int p = (int)(item >> 8), mbase = (int)(item & 255);
            const int Lp = (int)pcnt[p];
            const int mi = mbase + ln;
            const int arow = (mi < Lp) ? (int)plist[p][mi] : (int)plist[p][0];
            const u16* xr = &xf[arow][0];
            const u16* wb = wp1f + (size_t)p * 32768 + (size_t)lane * 8;
            f16x8 w20 = *(const f16x8*)(wp2f + p * 2048 + 0 * 512 + lane * 8);
            f16x8 w21 = *(const f16x8*)(wp2f + p * 2048 + 1 * 512 + lane * 8);
            f16x8 w22 = *(const f16x8*)(wp2f + p * 2048 + 2 * 512 + lane * 8);
            f16x8 w23 = *(const f16x8*)(wp2f + p * 2048 + 3 * 512 + lane * 8);
            f32x4 a0={0.f,0.f,0.f,0.f}, a1=a0, a2=a0, a3=a0, a4=a0, a5=a0, a6=a0, a7=a0;
            f16x8 c0,c1,c2,c3,c4,c5,c6,c7, d0,d1,d2,d3,d4,d5,d6,d7;
            PLD(c,0);
            PLD(d,1); PMF(c,0);
            PLD(c,2); PMF(d,1);
            PLD(d,3); PMF(c,2);
            PLD(c,4); PMF(d,3);
            PLD(d,5); PMF(c,4);
            PLD(c,6); PMF(d,5);
            PLD(d,7); PMF(c,6);
            PMF(d,7);
            u16* hp = hl + w * 2240;                 // [16][140]
            HPS(a0,0); HPS(a1,1); HPS(a2,2); HPS(a3,3);
            HPS(a4,4); HPS(a5,5); HPS(a6,6); HPS(a7,7);
            f32x4 po = (f32x4){0.f,0.f,0.f,0.f};
            po = MF(LH(0), w20, po);
            po = MF(LH(1), w21, po);
            po = MF(LH(2), w22, po);
            po = MF(LH(3), w23, po);
            if (ln < 10) {
                float b2 = bp2[p * 10 + ln];
                #pragma unroll
                for (int r = 0; r < 4; ++r) {
                    int mi2 = mbase + quad * 4 + r;
                    if (mi2 < Lp)
                        atomicAdd(&oacc[plist[p][mi2]][ln], po[r] + b2);
                }
            }
        }
    }
    __syncthreads();

    for (int i = t; i < 320; i += 256)
        out[(size_t)row0 * 10 + i] = ((float*)lg)[i] + ((float*)oacc)[i];
}

// ---- fix layer-1 macros ----
#define FLD(S,KK) \
    S##h0 = *(const f16x8*)(bbh + (KK)*512); \
    S##h1 = *(const f16x8*)(bbh + 4096 + (KK)*512); \
    S##l0 = *(const f16x8*)(bbl + (KK)*512); \
    S##l1 = *(const f16x8*)(bbl + 4096 + (KK)*512);
#define FCP(S,KK) { _Pragma("unroll") for (int m_=0;m_<4;++m_){ \
    f16x8 ah_=*(const f16x8*)(&xfh[m_*16+ln][(KK)*32+quad*8]); \
    f16x8 al_=*(const f16x8*)(&xfl[m_*16+ln][(KK)*32+quad*8]); \
    accH[m_][0]=MF(ah_,S##h0,accH[m_][0]); accS[m_][0]=MF(ah_,S##l0,accS[m_][0]); accS[m_][0]=MF(al_,S##h0,accS[m_][0]); \
    accH[m_][1]=MF(ah_,S##h1,accH[m_][1]); accS[m_][1]=MF(ah_,S##l1,accS[m_][1]); accS[m_][1]=MF(al_,S##h1,accS[m_][1]); } }
#define F2L(WH, WL, KK) \
    WH = *(const f16x8*)(wt2f + (hl*8+(KK))*512 + lane*8); \
    WL = *(const f16x8*)(wt2g + (hl*8+(KK))*512 + lane*8);
#define F2C(WH, WL, KK) { int hidx_=(w*16+ln)*264 + (KK)*32 + quad*8; \
    f16x8 hah_=*(const f16x8*)(&hb2[0][hidx_]); f16x8 hal_=*(const f16x8*)(&hb2[1][hidx_]); \
    acc2h=MF(hah_,WH,acc2h); acc2s=MF(hah_,WL,acc2s); acc2s=MF(hal_,WH,acc2s); }

// ---------------------------------------------------------------------------
// fix: high-precision recompute for margin-flagged rows, MFMA throughout.
// Split-f16 (hi + 2048*lo) layer1+2 reproduces fp32 logits to ~1e-7 ->
// exact bitmap; patch nets plain f16 MFMA. Alternating named-reg prefetch.
// ---------------------------------------------------------------------------
__global__ __launch_bounds__(512, 1) void fix_kernel(
    const float* __restrict__ x, const float* __restrict__ bt1,
    const float* __restrict__ bt2,
    const float* __restrict__ bp1, const float* __restrict__ bp2,
    const int* __restrict__ rdd,
    const u16* __restrict__ wt1f, const u16* __restrict__ wt1g,
    const u16* __restrict__ wt2f, const u16* __restrict__ wt2g,
    const u16* __restrict__ wp1f, const u16* __restrict__ wp2f,
    const u32* __restrict__ gcnt, const u32* __restrict__ glist,
    float* __restrict__ out)
{
    __shared__ u16 xfh[64][264];
    __shared__ u16 xfl[64][264];
    __shared__ u16 hb2[2][16896];    // h hi/lo halves; reused as patch hp
    __shared__ float lg[64][10];
    __shared__ float oacc[64][10];
    __shared__ u32 rows[64];
    __shared__ u32 plist[10][64];
    __shared__ u32 pcnt[10];
    __shared__ int rdds[20];
    __shared__ u32 wq[40];
    __shared__ u32 nwork;
    // ~143 KB -> 1 block/CU

    const int t = threadIdx.x;
    const int lane = t & 63;
    const int w = t >> 6;
    const int ln = lane & 15;
    const int quad = lane >> 4;
    const u32 cnt = gcnt[0];
    if (t < 20) rdds[t] = rdd[t];

    for (u32 base = blockIdx.x * 64; base < cnt; base += gridDim.x * 64) {
        __syncthreads();
        const int R = (int)min(64u, cnt - base);
        if (t < 64) rows[t] = glist[base + (t < R ? t : 0)];
        if (t < 10) pcnt[t] = 0;
        if (t == 0) nwork = 0;
        for (int i = t; i < 640; i += 512) ((float*)oacc)[i] = 0.f;
        __syncthreads();

        // ---- gather flagged x rows -> hi/lo f16 LDS ----
        #pragma unroll
        for (int i = 0; i < 8; ++i) {
            int f = t + 512 * i;
            int r = f >> 6, c4 = f & 63;
            float4 v = *(const float4*)(x + (size_t)rows[r] * 256 + c4 * 4);
            f16 h0 = (f16)v.x, h1 = (f16)v.y, h2 = (f16)v.z, h3 = (f16)v.w;
            u16 q0 = __builtin_bit_cast(u16, h0), q1 = __builtin_bit_cast(u16, h1);
            u16 q2 = __builtin_bit_cast(u16, h2), q3 = __builtin_bit_cast(u16, h3);
            u16 l0 = f16b(LSC * (v.x - (float)h0)), l1 = f16b(LSC * (v.y - (float)h1));
            u16 l2 = f16b(LSC * (v.z - (float)h2)), l3 = f16b(LSC * (v.w - (float)h3));
            uint2 hw = { (u32)q0 | ((u32)q1 << 16), (u32)q2 | ((u32)q3 << 16) };
            uint2 lw = { (u32)l0 | ((u32)l1 << 16), (u32)l2 | ((u32)l3 << 16) };
            *(uint2*)&xfh[r][c4 * 4] = hw;
            *(uint2*)&xfl[r][c4 * 4] = lw;
        }
        __syncthreads();

        // ---- layer 1 split-f16 (3 MFMA) + layer 2 split-f16 (3 MFMA) ----
        f32x4 acc2h = (f32x4){0.f,0.f,0.f,0.f};
        f32x4 acc2s = (f32x4){0.f,0.f,0.f,0.f};
        for (int hl = 0; hl < 2; ++hl) {
            f32x4 accH[4][2], accS[4][2];
            #pragma unroll
            for (int m = 0; m < 4; ++m)
                #pragma unroll
                for (int i2 = 0; i2 < 2; ++i2) {
                    accH[m][i2] = (f32x4){0.f,0.f,0.f,0.f};
                    accS[m][i2] = (f32x4){0.f,0.f,0.f,0.f};
                }
            const size_t boff = (size_t)(hl * 16 + w * 2) * 4096 + (size_t)lane * 8;
            const u16* bbh = wt1f + boff;
            const u16* bbl = wt1g + boff;
            f16x8 ch0, ch1, cl0, cl1, nh0, nh1, nl0, nl1;
            FLD(c,0);
            FLD(n,1); FCP(c,0);
            FLD(c,2); FCP(n,1);
            FLD(n,3); FCP(c,2);
            FLD(c,4); FCP(n,3);
            FLD(n,5); FCP(c,4);
            FLD(c,6); FCP(n,5);
            FLD(n,7); FCP(c,6);
            FCP(n,7);
            // bias + relu + hi/lo split -> hb2
            #pragma unroll
            for (int m = 0; m < 4; ++m)
                #pragma unroll
                for (int i2 = 0; i2 < 2; ++i2) {
                    int nloc = w * 32 + i2 * 16 + ln;
                    float bias = bt1[hl * 256 + nloc];
                    #pragma unroll
                    for (int r = 0; r < 4; ++r) {
                        float hv = accH[m][i2][r] + accS[m][i2][r] * LSCI + bias;
                        hv = hv > 0.f ? hv : 0.f;
                        f16 hh = (f16)hv;
                        int idx = (m * 16 + quad * 4 + r) * 264 + nloc;
                        hb2[0][idx] = __builtin_bit_cast(u16, hh);
                        hb2[1][idx] = f16b(LSC * (hv - (float)hh));
                    }
                }
            __syncthreads();
            if (w < 4) {
                f16x8 whc, wlc, whn, wln;
                F2L(whc, wlc, 0);
                F2L(whn, wln, 1); F2C(whc, wlc, 0);
                F2L(whc, wlc, 2); F2C(whn, wln, 1);
                F2L(whn, wln, 3); F2C(whc, wlc, 2);
                F2L(whc, wlc, 4); F2C(whn, wln, 3);
                F2L(whn, wln, 5); F2C(whc, wlc, 4);
                F2L(whc, wlc, 6); F2C(whn, wln, 5);
                F2L(whn, wln, 7); F2C(whc, wlc, 6);
                F2C(whn, wln, 7);
            }
            __syncthreads();
        }
        if (w < 4 && ln < 10) {
            #pragma unroll
            for (int r = 0; r < 4; ++r)
                lg[w * 16 + quad * 4 + r][ln] = acc2h[r] + acc2s[r] * LSCI + bt2[ln];
        }
        __syncthreads();

        // ---- exact bitmap + per-patch row lists ----
        if (t < R) {
            float l[10];
            #pragma unroll
            for (int c = 0; c < 10; ++c) l[c] = lg[t][c];
            float b0v = -1e30f; int i0 = 0;
            #pragma unroll
            for (int c = 0; c < 10; ++c) if (l[c] > b0v) { b0v = l[c]; i0 = c; }
            float b1v = -1e30f; int i1 = 0;
            #pragma unroll
            for (int c = 0; c < 10; ++c) { if (c == i0) continue; if (l[c] > b1v) { b1v = l[c]; i1 = c; } }
            u32 exact = 0, fb = 0;
            #pragma unroll
            for (int p = 0; p < 10; ++p) {
                int a = rdds[2 * p], bq = rdds[2 * p + 1];
                if (i0 == a && i1 == bq) exact |= 1u << p;
                if (i0 == a)             fb    |= 1u << p;
            }
            u32 bits = exact ? exact : fb;
            while (bits) {
                int p = __ffs(bits) - 1;
                bits &= bits - 1;
                u32 idx = atomicAdd(&pcnt[p], 1u);
                plist[p][idx] = (u32)t;
            }
        }
        __syncthreads();
        if (t < 10) {
            int L = (int)pcnt[t];
            for (int b2i = 0; b2i < L; b2i += 16) {
                u32 e = atomicAdd(&nwork, 1u);
                wq[e] = ((u32)t << 8) | (u32)b2i;
            }
        }
        __syncthreads();

        // ---- patch nets: flattened 8-frag named alternation ----
        {
            const u32 nw = nwork;
            u16* hbase = &hb2[0][0];
            for (u32 ii = w; ii < nw; ii += 8) {
                const u32 item = wq[ii];
                const int p = (int)(item >> 8), mbase = (int)(item & 255);
                const int Lp = (int)pcnt[p];
                const int mi = mbase + ln;
                const int arow = (mi < Lp) ? (int)plist[p][mi] : (int)plist[p][0];
                const u16* xr = &xfh[arow][0];
                const u16* wb = wp1f + (size_t)p * 32768 + (size_t)lane * 8;
                f16x8 w20 = *(const f16x8*)(wp2f + p * 2048 + 0 * 512 + lane * 8);
                f16x8 w21 = *(const f16x8*)(wp2f + p * 2048 + 1 * 512 + lane * 8);
                f16x8 w22 = *(const f16x8*)(wp2f + p * 2048 + 2 * 512 + lane * 8);
                f16x8 w23 = *(const f16x8*)(wp2f + p * 2048 + 3 * 512 + lane * 8);
                f32x4 a0={0.f,0.f,0.f,0.f}, a1=a0, a2=a0, a3=a0, a4=a0, a5=a0, a6=a0, a7=a0;
                f16x8 c0,c1,c2,c3,c4,c5,c6,c7, d0,d1,d2,d3,d4,d5,d6,d7;
                PLD(c,0);
                PLD(d,1); PMF(c,0);
                PLD(c,2); PMF(d,1);
                PLD(d,3); PMF(c,2);
                PLD(c,4); PMF(d,3);
                PLD(d,5); PMF(c,4);
                PLD(c,6); PMF(d,5);
                PLD(d,7); PMF(c,6);
                PMF(d,7);
                u16* hp = hbase + w * 2240;          // [16][140]
                HPS(a0,0); HPS(a1,1); HPS(a2,2); HPS(a3,3);
                HPS(a4,4); HPS(a5,5); HPS(a6,6); HPS(a7,7);
                f32x4 po = (f32x4){0.f,0.f,0.f,0.f};
                po = MF(LH(0), w20, po);
                po = MF(LH(1), w21, po);
                po = MF(LH(2), w22, po);
                po = MF(LH(3), w23, po);
                if (ln < 10) {
                    float b2 = bp2[p * 10 + ln];
                    #pragma unroll
                    for (int r = 0; r < 4; ++r) {
                        int mi2 = mbase + quad * 4 + r;
                        if (mi2 < Lp)
                            atomicAdd(&oacc[plist[p][mi2]][ln], po[r] + b2);
                    }
                }
            }
        }
        __syncthreads();

        for (int i = t; i < R * 10; i += 512) {
            int r = i / 10, c = i % 10;
            out[(size_t)rows[r] * 10 + c] = lg[r][c] + oacc[r][c];
        }
    }
}

extern "C" void kernel_launch(void* const* d_in, const int* in_sizes, int n_in,
                              void* d_out, int out_size, void* d_ws, size_t ws_size,
                              hipStream_t stream) {
    const float* x   = (const float*)d_in[0];
    const float* Wt1 = (const float*)d_in[1];
    const float* bt1 = (const float*)d_in[2];
    const float* Wt2 = (const float*)d_in[3];
    const float* bt2 = (const float*)d_in[4];
    const float* Wp1 = (const float*)d_in[5];
    const float* bp1 = (const float*)d_in[6];
    const float* Wp2 = (const float*)d_in[7];
    const float* bp2 = (const float*)d_in[8];
    const int* rdd = (const int*)d_in[9];
    float* out = (float*)d_out;

    u16* wt1f = (u16*)d_ws;                 // 131072 u16
    u16* wt1g = wt1f + 131072;              // 131072 u16
    u16* wp1f = wt1g + 131072;              // 327680 u16
    u16* wt2f = wp1f + 327680;              // 8192 u16
    u16* wt2g = wt2f + 8192;                // 8192 u16
    u16* wp2f = wt2g + 8192;                // 20480 u16
    u32* gcnt  = (u32*)(wp2f + 20480);      // 1 (+pad to 16)
    u32* glist = gcnt + 16;                 // 65536 u32

    hipLaunchKernelGGL(conv_kernel, dim3(113), dim3(256), 0, stream,
                       Wt1, Wp1, Wt2, Wp2, wt1f, wt1g, wp1f, wt2f, wt2g, wp2f, gcnt);
    hipLaunchKernelGGL(netsum_kernel, dim3(2048), dim3(256), 0, stream,
                       x, bt1, bt2, bp1, bp2, rdd,
                       wt1f, wp1f, wt2f, wp2f, out, gcnt, glist);
    hipLaunchKernelGGL(fix_kernel, dim3(256), dim3(512), 0, stream,
                       x, bt1, bt2, bp1, bp2, rdd,
                       wt1f, wt1g, wt2f, wt2g, wp1f, wp2f,
                       gcnt, glist, out);
}

// Round 10
// 209.266 us; speedup vs baseline: 1.1583x; 1.0559x over previous
//
#include <hip/hip_runtime.h>

typedef unsigned int u32;
typedef unsigned short u16;
typedef _Float16 f16;
typedef __attribute__((ext_vector_type(8))) _Float16 f16x8;
typedef __attribute__((ext_vector_type(4))) float f32x4;

#define MARGIN 1e-2f
#define LSC 2048.0f          // lo-split scale (keeps lo terms normal in f16)
#define LSCI (1.0f/2048.0f)

__device__ __forceinline__ u16 f16b(float f) {
    return __builtin_bit_cast(u16, (f16)f);
}
__device__ __forceinline__ f32x4 MF(f16x8 a, f16x8 b, f32x4 c) {
    return __builtin_amdgcn_mfma_f32_16x16x32_f16(a, b, c, 0, 0, 0);
}
__device__ __forceinline__ uint4 pack8(const u16 v[8]) {
    uint4 pk;
    pk.x = (u32)v[0] | ((u32)v[1] << 16);
    pk.y = (u32)v[2] | ((u32)v[3] << 16);
    pk.z = (u32)v[4] | ((u32)v[5] << 16);
    pk.w = (u32)v[6] | ((u32)v[7] << 16);
    return pk;
}
// layer-2 A-frag rebuild from transposed h (stride 72 u16)
__device__ __forceinline__ f16x8 l2afrag(const u16* s, int kf, int quad, int row) {
    union { u16 q[8]; f16x8 v; } u;
    #pragma unroll
    for (int j = 0; j < 8; ++j) u.q[j] = s[(kf * 32 + quad * 8 + j) * 72 + row];
    return u.v;
}

// ---------------------------------------------------------------------------
// conv: weights -> f16 MFMA-fragment-linear layouts (hi + scaled-lo for the
// exact-fix path). frag(nf,kk) of [K x N]: lane l (ln=l&15, quad=l>>4) holds
// 8 f16 = W[kk*32+quad*8+j][nf*16+ln], at (nf*8+kk)*512 + l*8 (u16 units).
// ---------------------------------------------------------------------------
__global__ __launch_bounds__(256) void conv_kernel(
    const float* __restrict__ Wt1, const float* __restrict__ Wp1,
    const float* __restrict__ Wt2, const float* __restrict__ Wp2,
    u16* __restrict__ wt1f, u16* __restrict__ wt1g, u16* __restrict__ wp1f,
    u16* __restrict__ wt2f, u16* __restrict__ wt2g, u16* __restrict__ wp2f,
    u32* __restrict__ gcnt)
{
    __shared__ float tile[64][68];
    const int t = threadIdx.x;
    const int b = blockIdx.x;

    if (b == 112) {
        if (t == 0) gcnt[0] = 0;
        for (int cc = t; cc < 1024; cc += 256) {
            int kk = cc >> 6, l = cc & 63, ln = l & 15, quad = l >> 4;
            u16 vh[8], vl[8];
            #pragma unroll
            for (int j = 0; j < 8; ++j) {
                int k = kk * 32 + quad * 8 + j;
                float f = (ln < 10) ? Wt2[k * 10 + ln] : 0.f;
                f16 h = (f16)f;
                vh[j] = __builtin_bit_cast(u16, h);
                vl[j] = f16b(LSC * (f - (float)h));
            }
            *(uint4*)(wt2f + kk * 512 + l * 8) = pack8(vh);
            *(uint4*)(wt2g + kk * 512 + l * 8) = pack8(vl);
        }
        for (int cc = t; cc < 2560; cc += 256) {
            int p = cc >> 8, rem = cc & 255, kk = rem >> 6, l = rem & 63;
            int ln = l & 15, quad = (l >> 4) & 3;
            u16 v[8];
            #pragma unroll
            for (int j = 0; j < 8; ++j) {
                int k = kk * 32 + quad * 8 + j;
                v[j] = f16b(ln < 10 ? Wp2[p * 1280 + k * 10 + ln] : 0.f);
            }
            *(uint4*)(wp2f + p * 2048 + kk * 512 + l * 8) = pack8(v);
        }
        return;
    }

    const float* src; int src_ld;
    u16 *dsth, *dstl; int nf0, kk0;
    if (b < 32) {
        int kt = b & 3, nt = b >> 2;
        src = Wt1 + (size_t)(kt * 64) * 512 + nt * 64; src_ld = 512;
        dsth = wt1f; dstl = wt1g; nf0 = nt * 4; kk0 = kt * 2;
    } else {
        int j = b - 32, p = j >> 3, r = j & 7;
        int kt = r & 3, nt = r >> 2;
        src = Wp1 + (size_t)p * 32768 + (size_t)(kt * 64) * 128 + nt * 64; src_ld = 128;
        dsth = wp1f + p * 32768; dstl = nullptr; nf0 = nt * 4; kk0 = kt * 2;
    }
    {
        const int kr = t >> 2, c0 = (t & 3) * 16;
        #pragma unroll
        for (int u = 0; u < 4; ++u) {
            float4 v = *(const float4*)(src + (size_t)kr * src_ld + c0 + u * 4);
            tile[kr][c0 + u*4 + 0] = v.x;
            tile[kr][c0 + u*4 + 1] = v.y;
            tile[kr][c0 + u*4 + 2] = v.z;
            tile[kr][c0 + u*4 + 3] = v.w;
        }
    }
    __syncthreads();
    #pragma unroll
    for (int s = 0; s < 2; ++s) {
        int cc = t + 256 * s;
        int l = cc & 63, fp = cc >> 6, nfl = fp >> 1, kkl = fp & 1;
        int ln = l & 15, quad = (l >> 4) & 3;
        int nloc = nfl * 16 + ln, kloc = kkl * 32 + quad * 8;
        u16 vh[8], vl[8];
        #pragma unroll
        for (int j = 0; j < 8; ++j) {
            float f = tile[kloc + j][nloc];
            f16 h = (f16)f;
            vh[j] = __builtin_bit_cast(u16, h);
            vl[j] = f16b(LSC * (f - (float)h));
        }
        size_t off = (size_t)((nf0 + nfl) * 8 + (kk0 + kkl)) * 512 + l * 8;
        *(uint4*)(dsth + off) = pack8(vh);
        if (dstl) *(uint4*)(dstl + off) = pack8(vl);
    }
}

// ---- netsum v9 layer-1 macros ----
// wave w: mg = w&3 (16-row group, A hoisted in a0..a7), h2 = w>>2 (n-half).
// per quarter the wave's 32 B-frags are contiguous: (Q*64 + h2*32 + j)*512.
#define LDQ(Q,J) (*(const f16x8*)(wt1f + (size_t)((Q)*64 + h2*32 + (J)) * 512 + lane*8))
#define LDT(Q,K2) (*(const f16x8*)(wt2f + (size_t)((Q)*4+(K2))*512 + lane*8))

#define HSTORE(Q,NFL) { \
    const int colL = (h2*4+(NFL))*16 + ln; \
    const float bias = bt1[(Q)*128 + colL]; \
    ushort4 hv_; \
    { float h_=acc[0]+bias; h_=h_>0.f?h_:0.f; hv_.x=f16b(h_); } \
    { float h_=acc[1]+bias; h_=h_>0.f?h_:0.f; hv_.y=f16b(h_); } \
    { float h_=acc[2]+bias; h_=h_>0.f?h_:0.f; hv_.z=f16b(h_); } \
    { float h_=acc[3]+bias; h_=h_>0.f?h_:0.f; hv_.w=f16b(h_); } \
    *(ushort4*)(scratch + colL*72 + mg*16 + quad*4) = hv_; }

#define NFB_STD(Q,NFL) { f32x4 acc={0.f,0.f,0.f,0.f}; \
    acc=MF(a0,bA,acc); bA=LDQ(Q,(NFL)*8+4); \
    acc=MF(a1,bB,acc); bB=LDQ(Q,(NFL)*8+5); \
    acc=MF(a2,bC,acc); bC=LDQ(Q,(NFL)*8+6); \
    acc=MF(a3,bD,acc); bD=LDQ(Q,(NFL)*8+7); \
    acc=MF(a4,bA,acc); bA=LDQ(Q,(NFL)*8+8); \
    acc=MF(a5,bB,acc); bB=LDQ(Q,(NFL)*8+9); \
    acc=MF(a6,bC,acc); bC=LDQ(Q,(NFL)*8+10); \
    acc=MF(a7,bD,acc); bD=LDQ(Q,(NFL)*8+11); \
    HSTORE(Q,NFL) }

#define NFB_LAST(Q,QN) { f32x4 acc={0.f,0.f,0.f,0.f}; \
    acc=MF(a0,bA,acc); bA=LDQ(Q,28); \
    acc=MF(a1,bB,acc); bB=LDQ(Q,29); \
    acc=MF(a2,bC,acc); bC=LDQ(Q,30); \
    acc=MF(a3,bD,acc); bD=LDQ(Q,31); \
    acc=MF(a4,bA,acc); bA=LDQ(QN,0); \
    acc=MF(a5,bB,acc); bB=LDQ(QN,1); \
    acc=MF(a6,bC,acc); bC=LDQ(QN,2); \
    acc=MF(a7,bD,acc); bD=LDQ(QN,3); \
    HSTORE(Q,3) }

#define QUARTER9(Q,QN,LASTQ) \
    NFB_STD(Q,0) NFB_STD(Q,1) NFB_STD(Q,2) NFB_LAST(Q,QN) \
    __syncthreads(); \
    if (w < 4) { \
        f16x8 A0_=l2afrag(scratch,0,quad,w*16+ln), A1_=l2afrag(scratch,1,quad,w*16+ln); \
        f16x8 A2_=l2afrag(scratch,2,quad,w*16+ln), A3_=l2afrag(scratch,3,quad,w*16+ln); \
        acc2=MF(A0_,t0,acc2); acc2=MF(A1_,t1,acc2); \
        acc2=MF(A2_,t2,acc2); acc2=MF(A3_,t3,acc2); \
        if (!(LASTQ)) { t0=LDT((Q)+1,0); t1=LDT((Q)+1,1); t2=LDT((Q)+1,2); t3=LDT((Q)+1,3); } \
    } \
    __syncthreads();

// ---------------------------------------------------------------------------
// netsum v9: 64-row / 8-wave blocks (grid 1024). Wave owns fixed m-group ->
// A-frags hoisted once (removes all layer-1 A ds_reads, R5's dominant LDS
// cost). Depth-4 rotating B prefetch. h stored transposed (one ushort4 LDS
// write per tile, 4x fewer). Layer-2 rebuilds A-frags via scalar u16 reads.
// ---------------------------------------------------------------------------
__global__ __launch_bounds__(512, 2) void netsum_kernel(
    const float* __restrict__ x, const float* __restrict__ bt1,
    const float* __restrict__ bt2,
    const float* __restrict__ bp1, const float* __restrict__ bp2,
    const int* __restrict__ rdd,
    const u16* __restrict__ wt1f, const u16* __restrict__ wp1f,
    const u16* __restrict__ wt2f, const u16* __restrict__ wp2f,
    float* __restrict__ out, u32* __restrict__ gcnt, u32* __restrict__ glist)
{
    __shared__ u16 xf[64][264];      // 33792 B
    __shared__ u16 scratch[17920];   // 35840 B  hqT[128][72] (layer1) / hp 8x2176 (patch)
    __shared__ float lg[64][10];
    __shared__ float oacc[64][10];
    __shared__ u32 plist[10][64];
    __shared__ u32 pcnt[10];
    __shared__ int rdds[20];
    __shared__ u32 wq[40];
    __shared__ u32 nwork;
    // ~75.8 KB -> 2 blocks/CU

    const int t = threadIdx.x;
    const int lane = t & 63;
    const int w = t >> 6;
    const int ln = lane & 15;
    const int quad = lane >> 4;
    const int mg = w & 3;
    const int h2 = w >> 2;
    const int row0 = blockIdx.x * 64;

    if (t < 10) pcnt[t] = 0;
    if (t < 20) rdds[t] = rdd[t];
    if (t == 0) nwork = 0;
    for (int i = t; i < 640; i += 512) ((float*)oacc)[i] = 0.f;

    // ---- stage x -> f16 LDS (coalesced) ----
    #pragma unroll
    for (int i = 0; i < 8; ++i) {
        int f = t + 512 * i;
        int r = f >> 6, c4 = f & 63;
        float4 v = *(const float4*)(x + (size_t)(row0 + r) * 256 + c4 * 4);
        u16 q0 = f16b(v.x), q1 = f16b(v.y), q2 = f16b(v.z), q3 = f16b(v.w);
        uint2 pw = { (u32)q0 | ((u32)q1 << 16), (u32)q2 | ((u32)q3 << 16) };
        *(uint2*)&xf[r][c4 * 4] = pw;
    }
    // prologue B/T prefetch issued before the barrier (hidden under it)
    f16x8 bA = LDQ(0,0), bB = LDQ(0,1), bC = LDQ(0,2), bD = LDQ(0,3);
    f16x8 t0 = {}, t1 = {}, t2 = {}, t3 = {};
    if (w < 4) { t0 = LDT(0,0); t1 = LDT(0,1); t2 = LDT(0,2); t3 = LDT(0,3); }
    __syncthreads();

    // ---- hoist A-frags for this wave's fixed m-group (32 VGPR, once) ----
    f16x8 a0 = *(const f16x8*)(&xf[mg*16+ln][0*32 + quad*8]);
    f16x8 a1 = *(const f16x8*)(&xf[mg*16+ln][1*32 + quad*8]);
    f16x8 a2 = *(const f16x8*)(&xf[mg*16+ln][2*32 + quad*8]);
    f16x8 a3 = *(const f16x8*)(&xf[mg*16+ln][3*32 + quad*8]);
    f16x8 a4 = *(const f16x8*)(&xf[mg*16+ln][4*32 + quad*8]);
    f16x8 a5 = *(const f16x8*)(&xf[mg*16+ln][5*32 + quad*8]);
    f16x8 a6 = *(const f16x8*)(&xf[mg*16+ln][6*32 + quad*8]);
    f16x8 a7 = *(const f16x8*)(&xf[mg*16+ln][7*32 + quad*8]);

    f32x4 acc2 = (f32x4){0.f, 0.f, 0.f, 0.f};
    QUARTER9(0,1,0)
    QUARTER9(1,2,0)
    QUARTER9(2,3,0)
    QUARTER9(3,3,1)
    if (w < 4 && ln < 10) {
        #pragma unroll
        for (int r = 0; r < 4; ++r)
            lg[w * 16 + quad * 4 + r][ln] = acc2[r] + bt2[ln];
    }
    __syncthreads();

    // ---- margin flag (-> global list) + bitmap + per-patch row lists ----
    if (t < 64) {
        float l[10];
        #pragma unroll
        for (int c = 0; c < 10; ++c) l[c] = lg[t][c];
        float b0v = -1e30f; int i0 = 0;
        #pragma unroll
        for (int c = 0; c < 10; ++c) if (l[c] > b0v) { b0v = l[c]; i0 = c; }
        float b1v = -1e30f; int i1 = 0;
        #pragma unroll
        for (int c = 0; c < 10; ++c) { if (c == i0) continue; if (l[c] > b1v) { b1v = l[c]; i1 = c; } }
        float b2v = -1e30f;
        #pragma unroll
        for (int c = 0; c < 10; ++c) { if (c == i0 || c == i1) continue; if (l[c] > b2v) b2v = l[c]; }
        if (b0v - b1v < MARGIN || b1v - b2v < MARGIN) {
            u32 idx = atomicAdd(gcnt, 1u);
            glist[idx] = (u32)(row0 + t);
        }
        u32 exact = 0, fb = 0;
        #pragma unroll
        for (int p = 0; p < 10; ++p) {
            int a = rdds[2 * p], bq = rdds[2 * p + 1];
            if (i0 == a && i1 == bq) exact |= 1u << p;
            if (i0 == a)             fb    |= 1u << p;
        }
        u32 bits = exact ? exact : fb;
        while (bits) {
            int p = __ffs(bits) - 1;
            bits &= bits - 1;
            u32 idx = atomicAdd(&pcnt[p], 1u);
            plist[p][idx] = (u32)t;
        }
    }
    __syncthreads();
    if (t < 10) {
        int L = (int)pcnt[t];
        for (int base = 0; base < L; base += 16) {
            u32 e = atomicAdd(&nwork, 1u);
            wq[e] = ((u32)t << 8) | (u32)base;
        }
    }
    __syncthreads();

    // ---- gated patch nets: n in 2 groups of 4 frags, rotating prefetch (R5) ----
    {
        const u32 nw = nwork;
        for (u32 ii = w; ii < nw; ii += 8) {
            const u32 item = wq[ii];
            const int p = (int)(item >> 8), mbase = (int)(item & 255);
            const int Lp = (int)pcnt[p];
            const int mi = mbase + ln;
            const int arow = (mi < Lp) ? (int)plist[p][mi] : (int)plist[p][0];
            const u16* xr = &xf[arow][0];
            const u16* wb = wp1f + (size_t)p * 32768 + (size_t)lane * 8;
            u16* hp = &scratch[w * 2176];            // [16][136]
            #pragma unroll
            for (int g = 0; g < 2; ++g) {
                f32x4 acc4[4];
                #pragma unroll
                for (int i2 = 0; i2 < 4; ++i2) acc4[i2] = (f32x4){0.f,0.f,0.f,0.f};
                f16x8 wc4[4];
                #pragma unroll
                for (int i2 = 0; i2 < 4; ++i2)
                    wc4[i2] = *(const f16x8*)(wb + ((g * 4 + i2) * 8 + 0) * 512);
                #pragma unroll
                for (int kk = 0; kk < 8; ++kk) {
                    f16x8 wn4[4];
                    #pragma unroll
                    for (int i2 = 0; i2 < 4; ++i2) {
                        wn4[i2] = wc4[i2];
                        if (kk < 7)
                            wn4[i2] = *(const f16x8*)(wb + ((g * 4 + i2) * 8 + kk + 1) * 512);
                    }
                    f16x8 a = *(const f16x8*)(xr + kk * 32 + quad * 8);
                    #pragma unroll
                    for (int i2 = 0; i2 < 4; ++i2) acc4[i2] = MF(a, wc4[i2], acc4[i2]);
                    #pragma unroll
                    for (int i2 = 0; i2 < 4; ++i2) wc4[i2] = wn4[i2];
                }
                #pragma unroll
                for (int i2 = 0; i2 < 4; ++i2) {
                    const int i2g = g * 4 + i2;
                    float bias = bp1[p * 128 + i2g * 16 + ln];
                    #pragma unroll
                    for (int r = 0; r < 4; ++r) {
                        float hv = acc4[i2][r] + bias; hv = hv > 0.f ? hv : 0.f;
                        hp[(quad * 4 + r) * 136 + i2g * 16 + ln] = f16b(hv);
                    }
                }
            }
            f32x4 po = (f32x4){0.f,0.f,0.f,0.f};
            #pragma unroll
            for (int kk = 0; kk < 4; ++kk) {
                f16x8 ha = *(const f16x8*)(&hp[ln * 136 + kk * 32 + quad * 8]);
                f16x8 wb2 = *(const f16x8*)(wp2f + p * 2048 + kk * 512 + lane * 8);
                po = MF(ha, wb2, po);
            }
            if (ln < 10) {
                float b2 = bp2[p * 10 + ln];
                #pragma unroll
                for (int r = 0; r < 4; ++r) {
                    int mi2 = mbase + quad * 4 + r;
                    if (mi2 < Lp)
                        atomicAdd(&oacc[plist[p][mi2]][ln], po[r] + b2);
                }
            }
        }
    }
    __syncthreads();

    for (int i = t; i < 640; i += 512)
        out[(size_t)row0 * 10 + i] = ((float*)lg)[i] + ((float*)oacc)[i];
}

// ---- fix layer-1 macros ----
#define FLD(S,KK) \
    S##h0 = *(const f16x8*)(bbh + (KK)*512); \
    S##h1 = *(const f16x8*)(bbh + 4096 + (KK)*512); \
    S##l0 = *(const f16x8*)(bbl + (KK)*512); \
    S##l1 = *(const f16x8*)(bbl + 4096 + (KK)*512);
#define FCP(S,KK) { _Pragma("unroll") for (int m_=0;m_<4;++m_){ \
    f16x8 ah_=*(const f16x8*)(&xfh[m_*16+ln][(KK)*32+quad*8]); \
    f16x8 al_=*(const f16x8*)(&xfl[m_*16+ln][(KK)*32+quad*8]); \
    accH[m_][0]=MF(ah_,S##h0,accH[m_][0]); accS[m_][0]=MF(ah_,S##l0,accS[m_][0]); accS[m_][0]=MF(al_,S##h0,accS[m_][0]); \
    accH[m_][1]=MF(ah_,S##h1,accH[m_][1]); accS[m_][1]=MF(ah_,S##l1,accS[m_][1]); accS[m_][1]=MF(al_,S##h1,accS[m_][1]); } }
#define F2L(WH, WL, KK) \
    WH = *(const f16x8*)(wt2f + (hl*8+(KK))*512 + lane*8); \
    WL = *(const f16x8*)(wt2g + (hl*8+(KK))*512 + lane*8);
#define F2C(WH, WL, KK) { int hidx_=(w*16+ln)*264 + (KK)*32 + quad*8; \
    f16x8 hah_=*(const f16x8*)(&hb2[0][hidx_]); f16x8 hal_=*(const f16x8*)(&hb2[1][hidx_]); \
    acc2h=MF(hah_,WH,acc2h); acc2s=MF(hah_,WL,acc2s); acc2s=MF(hal_,WH,acc2s); }

// ---------------------------------------------------------------------------
// fix: high-precision recompute for margin-flagged rows, MFMA throughout.
// ---------------------------------------------------------------------------
__global__ __launch_bounds__(512, 1) void fix_kernel(
    const float* __restrict__ x, const float* __restrict__ bt1,
    const float* __restrict__ bt2,
    const float* __restrict__ bp1, const float* __restrict__ bp2,
    const int* __restrict__ rdd,
    const u16* __restrict__ wt1f, const u16* __restrict__ wt1g,
    const u16* __restrict__ wt2f, const u16* __restrict__ wt2g,
    const u16* __restrict__ wp1f, const u16* __restrict__ wp2f,
    const u32* __restrict__ gcnt, const u32* __restrict__ glist,
    float* __restrict__ out)
{
    __shared__ u16 xfh[64][264];
    __shared__ u16 xfl[64][264];
    __shared__ u16 hb2[2][16896];
    __shared__ float lg[64][10];
    __shared__ float oacc[64][10];
    __shared__ u32 rows[64];
    __shared__ u32 plist[10][64];
    __shared__ u32 pcnt[10];
    __shared__ int rdds[20];
    __shared__ u32 wq[40];
    __shared__ u32 nwork;

    const int t = threadIdx.x;
    const int lane = t & 63;
    const int w = t >> 6;
    const int ln = lane & 15;
    const int quad = lane >> 4;
    const u32 cnt = gcnt[0];
    if (t < 20) rdds[t] = rdd[t];

    for (u32 base = blockIdx.x * 64; base < cnt; base += gridDim.x * 64) {
        __syncthreads();
        const int R = (int)min(64u, cnt - base);
        if (t < 64) rows[t] = glist[base + (t < R ? t : 0)];
        if (t < 10) pcnt[t] = 0;
        if (t == 0) nwork = 0;
        for (int i = t; i < 640; i += 512) ((float*)oacc)[i] = 0.f;
        __syncthreads();

        #pragma unroll
        for (int i = 0; i < 8; ++i) {
            int f = t + 512 * i;
            int r = f >> 6, c4 = f & 63;
            float4 v = *(const float4*)(x + (size_t)rows[r] * 256 + c4 * 4);
            f16 h0 = (f16)v.x, h1 = (f16)v.y, h2 = (f16)v.z, h3 = (f16)v.w;
            u16 q0 = __builtin_bit_cast(u16, h0), q1 = __builtin_bit_cast(u16, h1);
            u16 q2 = __builtin_bit_cast(u16, h2), q3 = __builtin_bit_cast(u16, h3);
            u16 l0 = f16b(LSC * (v.x - (float)h0)), l1 = f16b(LSC * (v.y - (float)h1));
            u16 l2 = f16b(LSC * (v.z - (float)h2)), l3 = f16b(LSC * (v.w - (float)h3));
            uint2 hw = { (u32)q0 | ((u32)q1 << 16), (u32)q2 | ((u32)q3 << 16) };
            uint2 lw = { (u32)l0 | ((u32)l1 << 16), (u32)l2 | ((u32)l3 << 16) };
            *(uint2*)&xfh[r][c4 * 4] = hw;
            *(uint2*)&xfl[r][c4 * 4] = lw;
        }
        __syncthreads();

        f32x4 acc2h = (f32x4){0.f,0.f,0.f,0.f};
        f32x4 acc2s = (f32x4){0.f,0.f,0.f,0.f};
        for (int hl = 0; hl < 2; ++hl) {
            f32x4 accH[4][2], accS[4][2];
            #pragma unroll
            for (int m = 0; m < 4; ++m)
                #pragma unroll
                for (int i2 = 0; i2 < 2; ++i2) {
                    accH[m][i2] = (f32x4){0.f,0.f,0.f,0.f};
                    accS[m][i2] = (f32x4){0.f,0.f,0.f,0.f};
                }
            const size_t boff = (size_t)(hl * 16 + w * 2) * 4096 + (size_t)lane * 8;
            const u16* bbh = wt1f + boff;
            const u16* bbl = wt1g + boff;
            f16x8 ch0, ch1, cl0, cl1, nh0, nh1, nl0, nl1;
            FLD(c,0);
            FLD(n,1); FCP(c,0);
            FLD(c,2); FCP(n,1);
            FLD(n,3); FCP(c,2);
            FLD(c,4); FCP(n,3);
            FLD(n,5); FCP(c,4);
            FLD(c,6); FCP(n,5);
            FLD(n,7); FCP(c,6);
            FCP(n,7);
            #pragma unroll
            for (int m = 0; m < 4; ++m)
                #pragma unroll
                for (int i2 = 0; i2 < 2; ++i2) {
                    int nloc = w * 32 + i2 * 16 + ln;
                    float bias = bt1[hl * 256 + nloc];
                    #pragma unroll
                    for (int r = 0; r < 4; ++r) {
                        float hv = accH[m][i2][r] + accS[m][i2][r] * LSCI + bias;
                        hv = hv > 0.f ? hv : 0.f;
                        f16 hh = (f16)hv;
                        int idx = (m * 16 + quad * 4 + r) * 264 + nloc;
                        hb2[0][idx] = __builtin_bit_cast(u16, hh);
                        hb2[1][idx] = f16b(LSC * (hv - (float)hh));
                    }
                }
            __syncthreads();
            if (w < 4) {
                f16x8 whc, wlc, whn, wln;
                F2L(whc, wlc, 0);
                F2L(whn, wln, 1); F2C(whc, wlc, 0);
                F2L(whc, wlc, 2); F2C(whn, wln, 1);
                F2L(whn, wln, 3); F2C(whc, wlc, 2);
                F2L(whc, wlc, 4); F2C(whn, wln, 3);
                F2L(whn, wln, 5); F2C(whc, wlc, 4);
                F2L(whc, wlc, 6); F2C(whn, wln, 5);
                F2L(whn, wln, 7); F2C(whc, wlc, 6);
                F2C(whn, wln, 7);
            }
            __syncthreads();
        }
        if (w < 4 && ln < 10) {
            #pragma unroll
            for (int r = 0; r < 4; ++r)
                lg[w * 16 + quad * 4 + r][ln] = acc2h[r] + acc2s[r] * LSCI + bt2[ln];
        }
        __syncthreads();

        if (t < R) {
            float l[10];
            #pragma unroll
            for (int c = 0; c < 10; ++c) l[c] = lg[t][c];
            float b0v = -1e30f; int i0 = 0;
            #pragma unroll
            for (int c = 0; c < 10; ++c) if (l[c] > b0v) { b0v = l[c]; i0 = c; }
            float b1v = -1e30f; int i1 = 0;
            #pragma unroll
            for (int c = 0; c < 10; ++c) { if (c == i0) continue; if (l[c] > b1v) { b1v = l[c]; i1 = c; } }
            u32 exact = 0, fb = 0;
            #pragma unroll
            for (int p = 0; p < 10; ++p) {
                int a = rdds[2 * p], bq = rdds[2 * p + 1];
                if (i0 == a && i1 == bq) exact |= 1u << p;
                if (i0 == a)             fb    |= 1u << p;
            }
            u32 bits = exact ? exact : fb;
            while (bits) {
                int p = __ffs(bits) - 1;
                bits &= bits - 1;
                u32 idx = atomicAdd(&pcnt[p], 1u);
                plist[p][idx] = (u32)t;
            }
        }
        __syncthreads();
        if (t < 10) {
            int L = (int)pcnt[t];
            for (int b2i = 0; b2i < L; b2i += 16) {
                u32 e = atomicAdd(&nwork, 1u);
                wq[e] = ((u32)t << 8) | (u32)b2i;
            }
        }
        __syncthreads();

        {
            const u32 nw = nwork;
            u16* hbase = &hb2[0][0];
            for (u32 ii = w; ii < nw; ii += 8) {
                const u32 item = wq[ii];
                const int p = (int)(item >> 8), mbase = (int)(item & 255);
                const int Lp = (int)pcnt[p];
                const int mi = mbase + ln;
                const int arow = (mi < Lp) ? (int)plist[p][mi] : (int)plist[p][0];
                const u16* xr = &xfh[arow][0];
                const u16* wb = wp1f + (size_t)p * 32768 + (size_t)lane * 8;
                u16* hp = hbase + w * 2176;
                #pragma unroll
                for (int g = 0; g < 2; ++g) {
                    f32x4 acc4[4];
                    #pragma unroll
                    for (int i2 = 0; i2 < 4; ++i2) acc4[i2] = (f32x4){0.f,0.f,0.f,0.f};
                    f16x8 wc4[4];
                    #pragma unroll
                    for (int i2 = 0; i2 < 4; ++i2)
                        wc4[i2] = *(const f16x8*)(wb + ((g * 4 + i2) * 8 + 0) * 512);
                    #pragma unroll
                    for (int kk = 0; kk < 8; ++kk) {
                        f16x8 wn4[4];
                        #pragma unroll
                        for (int i2 = 0; i2 < 4; ++i2) {
                            wn4[i2] = wc4[i2];
                            if (kk < 7)
                                wn4[i2] = *(const f16x8*)(wb + ((g * 4 + i2) * 8 + kk + 1) * 512);
                        }
                        f16x8 a = *(const f16x8*)(xr + kk * 32 + quad * 8);
                        #pragma unroll
                        for (int i2 = 0; i2 < 4; ++i2) acc4[i2] = MF(a, wc4[i2], acc4[i2]);
                        #pragma unroll
                        for (int i2 = 0; i2 < 4; ++i2) wc4[i2] = wn4[i2];
                    }
                    #pragma unroll
                    for (int i2 = 0; i2 < 4; ++i2) {
                        const int i2g = g * 4 + i2;
                        float bias = bp1[p * 128 + i2g * 16 + ln];
                        #pragma unroll
                        for (int r = 0; r < 4; ++r) {
                            float hv = acc4[i2][r] + bias; hv = hv > 0.f ? hv : 0.f;
                            hp[(quad * 4 + r) * 136 + i2g * 16 + ln] = f16b(hv);
                        }
                    }
                }
                f32x4 po = (f32x4){0.f,0.f,0.f,0.f};
                #pragma unroll
                for (int kk = 0; kk < 4; ++kk) {
                    f16x8 ha = *(const f16x8*)(&hp[ln * 136 + kk * 32 + quad * 8]);
                    f16x8 wb2 = *(const f16x8*)(wp2f + p * 2048 + kk * 512 + lane * 8);
                    po = MF(ha, wb2, po);
                }
                if (ln < 10) {
                    float b2 = bp2[p * 10 + ln];
                    #pragma unroll
                    for (int r = 0; r < 4; ++r) {
                        int mi2 = mbase + quad * 4 + r;
                        if (mi2 < Lp)
                            atomicAdd(&oacc[plist[p][mi2]][ln], po[r] + b2);
                    }
                }
            }
        }
        __syncthreads();

        for (int i = t; i < R * 10; i += 512) {
            int r = i / 10, c = i % 10;
            out[(size_t)rows[r] * 10 + c] = lg[r][c] + oacc[r][c];
        }
    }
}

extern "C" void kernel_launch(void* const* d_in, const int* in_sizes, int n_in,
                              void* d_out, int out_size, void* d_ws, size_t ws_size,
                              hipStream_t stream) {
    const float* x   = (const float*)d_in[0];
    const float* Wt1 = (const float*)d_in[1];
    const float* bt1 = (const float*)d_in[2];
    const float* Wt2 = (const float*)d_in[3];
    const float* bt2 = (const float*)d_in[4];
    const float* Wp1 = (const float*)d_in[5];
    const float* bp1 = (const float*)d_in[6];
    const float* Wp2 = (const float*)d_in[7];
    const float* bp2 = (const float*)d_in[8];
    const int* rdd = (const int*)d_in[9];
    float* out = (float*)d_out;

    u16* wt1f = (u16*)d_ws;                 // 131072 u16
    u16* wt1g = wt1f + 131072;              // 131072 u16
    u16* wp1f = wt1g + 131072;              // 327680 u16
    u16* wt2f = wp1f + 327680;              // 8192 u16
    u16* wt2g = wt2f + 8192;                // 8192 u16
    u16* wp2f = wt2g + 8192;                // 20480 u16
    u32* gcnt  = (u32*)(wp2f + 20480);      // 1 (+pad to 16)
    u32* glist = gcnt + 16;                 // 65536 u32

    hipLaunchKernelGGL(conv_kernel, dim3(113), dim3(256), 0, stream,
                       Wt1, Wp1, Wt2, Wp2, wt1f, wt1g, wp1f, wt2f, wt2g, wp2f, gcnt);
    hipLaunchKernelGGL(netsum_kernel, dim3(1024), dim3(512), 0, stream,
                       x, bt1, bt2, bp1, bp2, rdd,
                       wt1f, wp1f, wt2f, wp2f, out, gcnt, glist);
    hipLaunchKernelGGL(fix_kernel, dim3(256), dim3(512), 0, stream,
                       x, bt1, bt2, bp1, bp2, rdd,
                       wt1f, wt1g, wt2f, wt2g, wp1f, wp2f,
                       gcnt, glist, out);
}